// Round 9
// baseline (261.893 us; speedup 1.0000x reference)
//
#include <hip/hip_runtime.h>

// AirFitMultiHeadDNN — R18: vectorized uniform LDS reads (M: 15x b32 -> 4x
// b128; WB: -> 2x b128). Evidence R17: spill fixed (WRITE 71.7->2MB, VGPR
// 40), dur 80us with VALU 18%/HBM 22%/conflicts 0 => hidden pipe is LDS
// *issue count*: ~440 DS instrs/item (M's stride-20B triplet reads can't
// merge) ~= 30-45us of LDS issue per CU. R18 cuts DS/head 21 -> 9:
//   T   : stride-6 hv2 rows, b64+b64+b32 (lane-divergent, conflict-free)
//   M[h]: 16 hv2 = 64B, 16B-aligned -> 4x ds_read_b128 (uniform broadcast)
//   WB[h]: 8 dwords -> 2x ds_read_b128
// Registers: +24 transient/head, fits (512,6)'s ~84-VGPR budget.
// Predicted: dur 80 -> ~55-62us; VALU ~25-28%; VGPR 72-84; WRITE stays
// ~2MB (re-spill tripwire); conflicts 0. If dur flat => DS theory wrong,
// next round ablates M reads to split the wall.

#define HH   20
#define NEX  13
#define NT   512

// ws dword-slot layout
#define WS_T   0                 // T16[h][idx][p] : 20*13*6 = 1560 (p=5 pad)
#define WS_M   1560              // M16[h][s]      : 20*16   = 320  (s=15 pad)
#define WS_WB  1880              // WB[h][s]       : 20*8    = 160
#define WS_END 2040              // 8,160 B

typedef _Float16 hv2 __attribute__((ext_vector_type(2)));

__device__ __forceinline__ float softplus_fast(float x) {
    return fmaxf(x, 0.0f) + __logf(1.0f + __expf(-fabsf(x)));
}

__device__ __forceinline__ float fdot2f(hv2 a, hv2 b, float c) {
#if __has_builtin(__builtin_amdgcn_fdot2)
    return __builtin_amdgcn_fdot2(a, b, c, false);
#else
    return fmaf((float)a.x, (float)b.x, fmaf((float)a.y, (float)b.y, c));
#endif
}

__device__ __forceinline__ hv2 cvt_pk(float x, float y) {
#if __has_builtin(__builtin_amdgcn_cvt_pkrtz)
    return __builtin_bit_cast(hv2, __builtin_amdgcn_cvt_pkrtz(x, y));
#else
    return hv2{ (_Float16)x, (_Float16)y };
#endif
}

// -------- setup: fold weights into fp16 T16/M16 + WB rows --------
__global__ void airfit_setup(const float* __restrict__ emb,
                             const float* __restrict__ Wf,
                             const float* __restrict__ bf,
                             const float* __restrict__ W1,
                             const float* __restrict__ b1,
                             const float* __restrict__ W2,
                             const float* __restrict__ b2,
                             const float* __restrict__ Wo,
                             float* __restrict__ ws)
{
    int t = blockIdx.x * 256 + threadIdx.x;
    hv2* wsh = reinterpret_cast<hv2*>(ws);

    if (t < HH * NEX * 6) {                      // T16[h][idx][p], p=5 pad
        int h = t / (NEX * 6), r = t % (NEX * 6), idx = r / 6, p = r % 6;
        float v[2] = { 0.0f, 0.0f };
        if (p < 5) {
            for (int s = 0; s < 2; ++s) {
                int o = 2 * p + s;
                float a = b1[h * 10 + o];
                for (int i = 0; i < 3; ++i)
                    a += emb[idx * 3 + i] * W1[(h * 8 + i) * 10 + o];
                for (int q = 0; q < 5; ++q)
                    a += bf[q] * W1[(h * 8 + 3 + q) * 10 + o];
                v[s] = a;
            }
        }
        wsh[WS_T + t] = hv2{ (_Float16)v[0], (_Float16)v[1] };
    }
    if (t < HH * 16) {                           // M16[h][c*5+pp], s=15 pad
        int h = t / 16, s = t % 16;
        float v[2] = { 0.0f, 0.0f };
        if (s < 15) {
            int c = s / 5, pp = s % 5;
            for (int sd = 0; sd < 2; ++sd) {
                int o = 2 * pp + sd;
                float a = 0.0f;
                for (int q = 0; q < 5; ++q)
                    a += Wf[c * 5 + q] * W1[(h * 8 + 3 + q) * 10 + o];
                v[sd] = a;
            }
        }
        wsh[WS_M + t] = hv2{ (_Float16)v[0], (_Float16)v[1] };
    }
    if (t < HH * 8) {                            // WB[h]: W2h*5, b2, Wo, pad
        int h = t / 8, s = t % 8;
        float outv = 0.0f;
        if (s < 5)
            outv = __builtin_bit_cast(float,
                       hv2{ (_Float16)W2[h * 10 + 2 * s],
                            (_Float16)W2[h * 10 + 2 * s + 1] });
        else if (s == 5) outv = b2[h];
        else if (s == 6) outv = Wo[h];
        ws[WS_WB + t] = outv;
    }
}

// -------- main: full item (20 heads) per thread --------
__global__ __launch_bounds__(NT, 6) void airfit_kernel(
    const int*   __restrict__ e,   const float* __restrict__ f,
    const float* __restrict__ ws,  const float* __restrict__ bo,
    float* __restrict__ out, int B)
{
    __shared__ __align__(16) float s_c[WS_END];  // 8,160 B

    const int tid  = threadIdx.x;
    const int base = blockIdx.x * NT;
    const int nIt  = min(NT, B - base);

    for (int t = tid; t < WS_END; t += NT) s_c[t] = ws[t];
    __syncthreads();                             // only barrier

    if (tid >= nIt) return;
    const int item = base + tid;

    // ---- e: 5x int4 (16B-aligned: item*80B) -> 20 nibbles in 3 dwords ----
    const int4* eg = reinterpret_cast<const int4*>(e + (size_t)item * HH);
    int4 e0 = eg[0], e1 = eg[1], e2 = eg[2], e3 = eg[3], e4 = eg[4];
    unsigned ew0 = (unsigned)(e0.x & 15)        | ((unsigned)(e0.y & 15) << 4)
                 | ((unsigned)(e0.z & 15) << 8) | ((unsigned)(e0.w & 15) << 12)
                 | ((unsigned)(e1.x & 15) << 16)| ((unsigned)(e1.y & 15) << 20)
                 | ((unsigned)(e1.z & 15) << 24)| ((unsigned)(e1.w & 15) << 28);
    unsigned ew1 = (unsigned)(e2.x & 15)        | ((unsigned)(e2.y & 15) << 4)
                 | ((unsigned)(e2.z & 15) << 8) | ((unsigned)(e2.w & 15) << 12)
                 | ((unsigned)(e3.x & 15) << 16)| ((unsigned)(e3.y & 15) << 20)
                 | ((unsigned)(e3.z & 15) << 24)| ((unsigned)(e3.w & 15) << 28);
    unsigned ew2 = (unsigned)(e4.x & 15)        | ((unsigned)(e4.y & 15) << 4)
                 | ((unsigned)(e4.z & 15) << 8) | ((unsigned)(e4.w & 15) << 12);

    // ---- f: 15x float4 (16B-aligned: item*240B), cvt_pkrtz immediately ----
    const float4* fg = reinterpret_cast<const float4*>(f + (size_t)item * 60);
    hv2 fh[30];
#pragma unroll
    for (int k = 0; k < 15; ++k) {
        float4 v = fg[k];
        fh[2 * k]     = cvt_pk(v.x, v.y);
        fh[2 * k + 1] = cvt_pk(v.z, v.w);
    }

    const hv2 lk2 = hv2{ (_Float16)0.01f, (_Float16)0.01f };
    const hv2* Tt = reinterpret_cast<const hv2*>(s_c + WS_T);

    float acc = bo[0];
#pragma unroll
    for (int h = 0; h < HH; ++h) {               // h compile-time
        unsigned word = (h < 8) ? ew0 : ((h < 16) ? ew1 : ew2);
        int idx = (int)((word >> (4 * (h & 7))) & 0xfu);

        const hv2* Tr = Tt + (h * NEX + idx) * 6;
        hv2 tp[5] = { Tr[0], Tr[1], Tr[2], Tr[3], Tr[4] };

        // M[h]: 64B uniform row -> 4x ds_read_b128 into registers
        const float4* Mh4 = reinterpret_cast<const float4*>(s_c + WS_M + h * 16);
        float4 m0 = Mh4[0], m1 = Mh4[1], m2 = Mh4[2], m3 = Mh4[3];
        hv2 Mr[16];
        *reinterpret_cast<float4*>(&Mr[0])  = m0;
        *reinterpret_cast<float4*>(&Mr[4])  = m1;
        *reinterpret_cast<float4*>(&Mr[8])  = m2;
        *reinterpret_cast<float4*>(&Mr[12]) = m3;

        // WB[h]: 32B uniform row -> 2x ds_read_b128
        const float4* wb4 = reinterpret_cast<const float4*>(s_c + WS_WB + h * 8);
        float4 w0 = wb4[0], w1 = wb4[1];
        float wbr[8];
        *reinterpret_cast<float4*>(&wbr[0]) = w0;
        *reinterpret_cast<float4*>(&wbr[4]) = w1;

        // f floats 3h..3h+2 out of fh[30] (pair index (3h)>>1, max 29)
        const int kb = (3 * h) >> 1;
        _Float16 x0, x1, x2;
        if ((h & 1) == 0) { x0 = fh[kb].x;  x1 = fh[kb].y;   x2 = fh[kb+1].x; }
        else              { x0 = fh[kb].y;  x1 = fh[kb+1].x; x2 = fh[kb+1].y; }
        hv2 g0 = hv2{ x0, x0 }, g1 = hv2{ x1, x1 }, g2 = hv2{ x2, x2 };

        float hacc = wbr[5];                     // b2[h]
#pragma unroll
        for (int p = 0; p < 5; ++p) {
            hv2 v = g0 * Mr[p] + tp[p];          // v_pk_fma_f16
            v = g1 * Mr[5 + p] + v;
            v = g2 * Mr[10 + p] + v;
            v = __builtin_elementwise_max(v, v * lk2);  // leaky
            hacc = fdot2f(v, __builtin_bit_cast(hv2, wbr[p]), hacc);
        }
        acc = fmaf(softplus_fast(hacc), wbr[6], acc);   // Wo[h]
    }

    out[item] = acc;                             // coalesced, no atomics
}

extern "C" void kernel_launch(void* const* d_in, const int* in_sizes, int n_in,
                              void* d_out, int out_size, void* d_ws, size_t ws_size,
                              hipStream_t stream) {
    const int*   e   = (const int*)  d_in[0];
    const float* f   = (const float*)d_in[1];
    const float* emb = (const float*)d_in[2];
    const float* Wf  = (const float*)d_in[3];
    const float* bf  = (const float*)d_in[4];
    const float* W1  = (const float*)d_in[5];
    const float* b1  = (const float*)d_in[6];
    const float* W2  = (const float*)d_in[7];
    const float* b2  = (const float*)d_in[8];
    const float* Wo  = (const float*)d_in[9];
    const float* bo  = (const float*)d_in[10];
    float* out = (float*)d_out;
    float* ws  = (float*)d_ws;

    int B = in_sizes[0] / HH;                    // e is (B, 20)

    int sblocks = (HH * NEX * 6 + 255) / 256;    // 7 blocks covers all tables
    airfit_setup<<<sblocks, 256, 0, stream>>>(emb, Wf, bf, W1, b1, W2, b2, Wo, ws);

    int blocks = (B + NT - 1) / NT;
    airfit_kernel<<<blocks, NT, 0, stream>>>(e, f, ws, bo, out, B);
}

// Round 10
// 258.849 us; speedup vs baseline: 1.0118x; 1.0118x over previous
//
#include <hip/hip_runtime.h>

// AirFitMultiHeadDNN — R19: SSA-clean b128 LDS reads + grouped f loads +
// exact-round grid.
// Evidence R18: VGPR 40->32, FETCH 108->268MB with WRITE flat at 2MB =>
// allocator REMATERIALIZED f from global per head (reads w/o writes) after
// (a) address-taken Mr[]/wbr[] defeated SROA and (b) +24 transients/head
// tipped regalloc. R17 baseline: 80us, VALU 18%, HBM 22%, conflicts 0,
// occupancy 51% (3 blocks/CU over 1024 blocks = 1.33 residency rounds).
// R19: (1) M[h] 64B + WB[h] 32B read as float4 SSA (ds_read_b128 by
// construction, brace-init arrays, compile-time indices only — no address
// escapes). DS/head 21 -> 9. (2) f in 5 groups of 3 float4 (12 floats = 4
// heads), cvt_pkrtz immediately, consumed in-group: peak live f ~18 regs,
// ranges too short to remat. (3) launch_bounds(512,8): 4 blocks/CU ->
// 1024 blocks = exactly 1 round, 32 waves/CU.
// Predicted: dur 80 -> ~58-68us; FETCH <=180MB (>=250 = group re-touch,
// revert); WRITE ~2MB (spill tripwire); VGPR 56-64; Occ ~75%; conflicts 0.

#define HH   20
#define NEX  13
#define NT   512

// ws dword-slot layout
#define WS_T   0                 // T16[h][idx][p] : 20*13*6 = 1560 (p=5 pad)
#define WS_M   1560              // M16[h][s]      : 20*16   = 320  (s=15 pad)
#define WS_WB  1880              // WB[h][s]       : 20*8    = 160
#define WS_END 2040              // 8,160 B

typedef _Float16 hv2 __attribute__((ext_vector_type(2)));

__device__ __forceinline__ float softplus_fast(float x) {
    return fmaxf(x, 0.0f) + __logf(1.0f + __expf(-fabsf(x)));
}

__device__ __forceinline__ float fdot2f(hv2 a, hv2 b, float c) {
#if __has_builtin(__builtin_amdgcn_fdot2)
    return __builtin_amdgcn_fdot2(a, b, c, false);
#else
    return fmaf((float)a.x, (float)b.x, fmaf((float)a.y, (float)b.y, c));
#endif
}

__device__ __forceinline__ hv2 cvt_pk(float x, float y) {
#if __has_builtin(__builtin_amdgcn_cvt_pkrtz)
    return __builtin_bit_cast(hv2, __builtin_amdgcn_cvt_pkrtz(x, y));
#else
    return hv2{ (_Float16)x, (_Float16)y };
#endif
}

// -------- setup: fold weights into fp16 T16/M16 + WB rows --------
__global__ void airfit_setup(const float* __restrict__ emb,
                             const float* __restrict__ Wf,
                             const float* __restrict__ bf,
                             const float* __restrict__ W1,
                             const float* __restrict__ b1,
                             const float* __restrict__ W2,
                             const float* __restrict__ b2,
                             const float* __restrict__ Wo,
                             float* __restrict__ ws)
{
    int t = blockIdx.x * 256 + threadIdx.x;
    hv2* wsh = reinterpret_cast<hv2*>(ws);

    if (t < HH * NEX * 6) {                      // T16[h][idx][p], p=5 pad
        int h = t / (NEX * 6), r = t % (NEX * 6), idx = r / 6, p = r % 6;
        float v[2] = { 0.0f, 0.0f };
        if (p < 5) {
            for (int s = 0; s < 2; ++s) {
                int o = 2 * p + s;
                float a = b1[h * 10 + o];
                for (int i = 0; i < 3; ++i)
                    a += emb[idx * 3 + i] * W1[(h * 8 + i) * 10 + o];
                for (int q = 0; q < 5; ++q)
                    a += bf[q] * W1[(h * 8 + 3 + q) * 10 + o];
                v[s] = a;
            }
        }
        wsh[WS_T + t] = hv2{ (_Float16)v[0], (_Float16)v[1] };
    }
    if (t < HH * 16) {                           // M16[h][c*5+pp], s=15 pad
        int h = t / 16, s = t % 16;
        float v[2] = { 0.0f, 0.0f };
        if (s < 15) {
            int c = s / 5, pp = s % 5;
            for (int sd = 0; sd < 2; ++sd) {
                int o = 2 * pp + sd;
                float a = 0.0f;
                for (int q = 0; q < 5; ++q)
                    a += Wf[c * 5 + q] * W1[(h * 8 + 3 + q) * 10 + o];
                v[sd] = a;
            }
        }
        wsh[WS_M + t] = hv2{ (_Float16)v[0], (_Float16)v[1] };
    }
    if (t < HH * 8) {                            // WB[h]: W2h*5, b2, Wo, pad
        int h = t / 8, s = t % 8;
        float outv = 0.0f;
        if (s < 5)
            outv = __builtin_bit_cast(float,
                       hv2{ (_Float16)W2[h * 10 + 2 * s],
                            (_Float16)W2[h * 10 + 2 * s + 1] });
        else if (s == 5) outv = b2[h];
        else if (s == 6) outv = Wo[h];
        ws[WS_WB + t] = outv;
    }
}

// -------- main: full item (20 heads) per thread, 5 f-groups --------
__global__ __launch_bounds__(NT, 8) void airfit_kernel(
    const int*   __restrict__ e,   const float* __restrict__ f,
    const float* __restrict__ ws,  const float* __restrict__ bo,
    float* __restrict__ out, int B)
{
    __shared__ __align__(16) float s_c[WS_END];  // 8,160 B

    const int tid  = threadIdx.x;
    const int base = blockIdx.x * NT;
    const int nIt  = min(NT, B - base);

    for (int t = tid; t < WS_END; t += NT) s_c[t] = ws[t];
    __syncthreads();                             // only barrier

    if (tid >= nIt) return;
    const int item = base + tid;

    // ---- e: 5x int4 (16B-aligned: item*80B) -> 20 nibbles in 3 dwords ----
    const int4* eg = reinterpret_cast<const int4*>(e + (size_t)item * HH);
    int4 e0 = eg[0], e1 = eg[1], e2 = eg[2], e3 = eg[3], e4 = eg[4];
    unsigned ew0 = (unsigned)(e0.x & 15)        | ((unsigned)(e0.y & 15) << 4)
                 | ((unsigned)(e0.z & 15) << 8) | ((unsigned)(e0.w & 15) << 12)
                 | ((unsigned)(e1.x & 15) << 16)| ((unsigned)(e1.y & 15) << 20)
                 | ((unsigned)(e1.z & 15) << 24)| ((unsigned)(e1.w & 15) << 28);
    unsigned ew1 = (unsigned)(e2.x & 15)        | ((unsigned)(e2.y & 15) << 4)
                 | ((unsigned)(e2.z & 15) << 8) | ((unsigned)(e2.w & 15) << 12)
                 | ((unsigned)(e3.x & 15) << 16)| ((unsigned)(e3.y & 15) << 20)
                 | ((unsigned)(e3.z & 15) << 24)| ((unsigned)(e3.w & 15) << 28);
    unsigned ew2 = (unsigned)(e4.x & 15)        | ((unsigned)(e4.y & 15) << 4)
                 | ((unsigned)(e4.z & 15) << 8) | ((unsigned)(e4.w & 15) << 12);

    const float4* fg = reinterpret_cast<const float4*>(f + (size_t)item * 60);
    const hv2*    Tt = reinterpret_cast<const hv2*>(s_c + WS_T);
    const hv2 lk2 = hv2{ (_Float16)0.01f, (_Float16)0.01f };

    float acc = bo[0];

#pragma unroll
    for (int gq = 0; gq < 5; ++gq) {             // 4 heads per group
        // ---- f group: 3x float4 = 12 floats = heads 4gq..4gq+3 ----
        float4 fa = fg[3 * gq], fb = fg[3 * gq + 1], fc4 = fg[3 * gq + 2];
        hv2 fc[6] = { cvt_pk(fa.x, fa.y), cvt_pk(fa.z, fa.w),
                      cvt_pk(fb.x, fb.y), cvt_pk(fb.z, fb.w),
                      cvt_pk(fc4.x, fc4.y), cvt_pk(fc4.z, fc4.w) };

        unsigned ewx = (gq < 2) ? ew0 : ((gq < 4) ? ew1 : ew2);
        unsigned gw  = (gq & 1) ? (ewx >> 16) : ewx;   // 4 nibbles

#pragma unroll
        for (int t = 0; t < 4; ++t) {
            const int h = 4 * gq + t;            // compile-time
            int idx = (int)((gw >> (4 * t)) & 0xfu);

            const hv2* Tr = Tt + (h * NEX + idx) * 6;
            hv2 tp[5] = { Tr[0], Tr[1], Tr[2], Tr[3], Tr[4] };

            // M[h]: 64B uniform row -> 4x ds_read_b128, pure SSA extract
            const float4* Mh4 =
                reinterpret_cast<const float4*>(s_c + WS_M + h * 16);
            float4 m0 = Mh4[0], m1 = Mh4[1], m2 = Mh4[2], m3 = Mh4[3];
            float mj[16] = { m0.x, m0.y, m0.z, m0.w,  m1.x, m1.y, m1.z, m1.w,
                             m2.x, m2.y, m2.z, m2.w,  m3.x, m3.y, m3.z, m3.w };

            // WB[h]: 32B uniform row -> 2x ds_read_b128
            const float4* wb4 =
                reinterpret_cast<const float4*>(s_c + WS_WB + h * 8);
            float4 w0 = wb4[0], w1 = wb4[1];
            float wj[5] = { w0.x, w0.y, w0.z, w0.w, w1.x };

            // f floats 3t..3t+2 within the group's 6 pairs
            const int kb = (3 * t) >> 1;
            _Float16 x0, x1, x2;
            if ((t & 1) == 0) { x0 = fc[kb].x;  x1 = fc[kb].y;   x2 = fc[kb+1].x; }
            else              { x0 = fc[kb].y;  x1 = fc[kb+1].x; x2 = fc[kb+1].y; }
            hv2 g0 = hv2{ x0, x0 }, g1 = hv2{ x1, x1 }, g2 = hv2{ x2, x2 };

            float hacc = w1.y;                   // b2[h]
#pragma unroll
            for (int p = 0; p < 5; ++p) {
                hv2 v = g0 * __builtin_bit_cast(hv2, mj[p])      + tp[p];
                v = g1 * __builtin_bit_cast(hv2, mj[5 + p])  + v;
                v = g2 * __builtin_bit_cast(hv2, mj[10 + p]) + v;
                v = __builtin_elementwise_max(v, v * lk2);   // leaky
                hacc = fdot2f(v, __builtin_bit_cast(hv2, wj[p]), hacc);
            }
            acc = fmaf(softplus_fast(hacc), w1.z, acc);      // Wo[h]
        }
    }

    out[item] = acc;                             // coalesced, no atomics
}

extern "C" void kernel_launch(void* const* d_in, const int* in_sizes, int n_in,
                              void* d_out, int out_size, void* d_ws, size_t ws_size,
                              hipStream_t stream) {
    const int*   e   = (const int*)  d_in[0];
    const float* f   = (const float*)d_in[1];
    const float* emb = (const float*)d_in[2];
    const float* Wf  = (const float*)d_in[3];
    const float* bf  = (const float*)d_in[4];
    const float* W1  = (const float*)d_in[5];
    const float* b1  = (const float*)d_in[6];
    const float* W2  = (const float*)d_in[7];
    const float* b2  = (const float*)d_in[8];
    const float* Wo  = (const float*)d_in[9];
    const float* bo  = (const float*)d_in[10];
    float* out = (float*)d_out;
    float* ws  = (float*)d_ws;

    int B = in_sizes[0] / HH;                    // e is (B, 20)

    int sblocks = (HH * NEX * 6 + 255) / 256;    // 7 blocks covers all tables
    airfit_setup<<<sblocks, 256, 0, stream>>>(emb, Wf, bf, W1, b1, W2, b2, Wo, ws);

    int blocks = (B + NT - 1) / NT;
    airfit_kernel<<<blocks, NT, 0, stream>>>(e, f, ws, bo, out, B);
}

// Round 11
// 244.381 us; speedup vs baseline: 1.0717x; 1.0592x over previous
//
#include <hip/hip_runtime.h>

// AirFitMultiHeadDNN — R20: R17 (batch f load, (512,6), 80.3us) + the R18
// INTENT done cleanly: M/WB via uniform ds_read_b128 in pure SSA form.
// Evidence R19: grouped-f tripwire fired (FETCH 261MB >= 250) — group
// time-spread re-fetches f ~2.2x from HBM after L2 eviction. Revert to
// R17's batch-15-float4 f path (FETCH 108MB, no spill).
// Evidence R17: dur 80us, VALU 18%, HBM 22%, conflicts 0 — wall is LDS
// ISSUE COUNT: ~25 DS instr/head (M = 15 scalar b32, unmergeable at 20B
// stride) ~= 40us/CU of LDS pipe. R20 cuts to 9/head (T b64+b64+b32,
// M 4x b128, WB 2x b128, all uniform-addr broadcasts) ~= 25us/CU.
// SSA discipline (R18 lesson): no address-taken locals — float4 values +
// brace-init arrays with compile-time indices only.
// Predicted: dur 80 -> 62-70us; FETCH 108-130MB (>=200 => b128 batch
// pathology, revert+pivot to 2 items/thread); WRITE ~2MB; VGPR 56-72.

#define HH   20
#define NEX  13
#define NT   512

// ws dword-slot layout
#define WS_T   0                 // T16[h][idx][p] : 20*13*6 = 1560 (p=5 pad)
#define WS_M   1560              // M16[h][s]      : 20*16   = 320  (s=15 pad)
#define WS_WB  1880              // WB[h][s]       : 20*8    = 160
#define WS_END 2040              // 8,160 B

typedef _Float16 hv2 __attribute__((ext_vector_type(2)));

__device__ __forceinline__ float softplus_fast(float x) {
    return fmaxf(x, 0.0f) + __logf(1.0f + __expf(-fabsf(x)));
}

__device__ __forceinline__ float fdot2f(hv2 a, hv2 b, float c) {
#if __has_builtin(__builtin_amdgcn_fdot2)
    return __builtin_amdgcn_fdot2(a, b, c, false);
#else
    return fmaf((float)a.x, (float)b.x, fmaf((float)a.y, (float)b.y, c));
#endif
}

__device__ __forceinline__ hv2 cvt_pk(float x, float y) {
#if __has_builtin(__builtin_amdgcn_cvt_pkrtz)
    return __builtin_bit_cast(hv2, __builtin_amdgcn_cvt_pkrtz(x, y));
#else
    return hv2{ (_Float16)x, (_Float16)y };
#endif
}

// -------- setup: fold weights into fp16 T16/M16 + WB rows --------
__global__ void airfit_setup(const float* __restrict__ emb,
                             const float* __restrict__ Wf,
                             const float* __restrict__ bf,
                             const float* __restrict__ W1,
                             const float* __restrict__ b1,
                             const float* __restrict__ W2,
                             const float* __restrict__ b2,
                             const float* __restrict__ Wo,
                             float* __restrict__ ws)
{
    int t = blockIdx.x * 256 + threadIdx.x;
    hv2* wsh = reinterpret_cast<hv2*>(ws);

    if (t < HH * NEX * 6) {                      // T16[h][idx][p], p=5 pad
        int h = t / (NEX * 6), r = t % (NEX * 6), idx = r / 6, p = r % 6;
        float v[2] = { 0.0f, 0.0f };
        if (p < 5) {
            for (int s = 0; s < 2; ++s) {
                int o = 2 * p + s;
                float a = b1[h * 10 + o];
                for (int i = 0; i < 3; ++i)
                    a += emb[idx * 3 + i] * W1[(h * 8 + i) * 10 + o];
                for (int q = 0; q < 5; ++q)
                    a += bf[q] * W1[(h * 8 + 3 + q) * 10 + o];
                v[s] = a;
            }
        }
        wsh[WS_T + t] = hv2{ (_Float16)v[0], (_Float16)v[1] };
    }
    if (t < HH * 16) {                           // M16[h][c*5+pp], s=15 pad
        int h = t / 16, s = t % 16;
        float v[2] = { 0.0f, 0.0f };
        if (s < 15) {
            int c = s / 5, pp = s % 5;
            for (int sd = 0; sd < 2; ++sd) {
                int o = 2 * pp + sd;
                float a = 0.0f;
                for (int q = 0; q < 5; ++q)
                    a += Wf[c * 5 + q] * W1[(h * 8 + 3 + q) * 10 + o];
                v[sd] = a;
            }
        }
        wsh[WS_M + t] = hv2{ (_Float16)v[0], (_Float16)v[1] };
    }
    if (t < HH * 8) {                            // WB[h]: W2h*5, b2, Wo, pad
        int h = t / 8, s = t % 8;
        float outv = 0.0f;
        if (s < 5)
            outv = __builtin_bit_cast(float,
                       hv2{ (_Float16)W2[h * 10 + 2 * s],
                            (_Float16)W2[h * 10 + 2 * s + 1] });
        else if (s == 5) outv = b2[h];
        else if (s == 6) outv = Wo[h];
        ws[WS_WB + t] = outv;
    }
}

// -------- main: full item (20 heads) per thread --------
__global__ __launch_bounds__(NT, 6) void airfit_kernel(
    const int*   __restrict__ e,   const float* __restrict__ f,
    const float* __restrict__ ws,  const float* __restrict__ bo,
    float* __restrict__ out, int B)
{
    __shared__ __align__(16) float s_c[WS_END];  // 8,160 B

    const int tid  = threadIdx.x;
    const int base = blockIdx.x * NT;
    const int nIt  = min(NT, B - base);

    for (int t = tid; t < WS_END; t += NT) s_c[t] = ws[t];
    __syncthreads();                             // only barrier

    if (tid >= nIt) return;
    const int item = base + tid;

    // ---- e: 5x int4 (16B-aligned: item*80B) -> 20 nibbles in 3 dwords ----
    const int4* eg = reinterpret_cast<const int4*>(e + (size_t)item * HH);
    int4 e0 = eg[0], e1 = eg[1], e2 = eg[2], e3 = eg[3], e4 = eg[4];
    unsigned ew0 = (unsigned)(e0.x & 15)        | ((unsigned)(e0.y & 15) << 4)
                 | ((unsigned)(e0.z & 15) << 8) | ((unsigned)(e0.w & 15) << 12)
                 | ((unsigned)(e1.x & 15) << 16)| ((unsigned)(e1.y & 15) << 20)
                 | ((unsigned)(e1.z & 15) << 24)| ((unsigned)(e1.w & 15) << 28);
    unsigned ew1 = (unsigned)(e2.x & 15)        | ((unsigned)(e2.y & 15) << 4)
                 | ((unsigned)(e2.z & 15) << 8) | ((unsigned)(e2.w & 15) << 12)
                 | ((unsigned)(e3.x & 15) << 16)| ((unsigned)(e3.y & 15) << 20)
                 | ((unsigned)(e3.z & 15) << 24)| ((unsigned)(e3.w & 15) << 28);
    unsigned ew2 = (unsigned)(e4.x & 15)        | ((unsigned)(e4.y & 15) << 4)
                 | ((unsigned)(e4.z & 15) << 8) | ((unsigned)(e4.w & 15) << 12);

    // ---- f: 15x float4 (16B-aligned: item*240B), cvt_pkrtz immediately ----
    const float4* fg = reinterpret_cast<const float4*>(f + (size_t)item * 60);
    hv2 fh[30];
#pragma unroll
    for (int k = 0; k < 15; ++k) {
        float4 v = fg[k];
        fh[2 * k]     = cvt_pk(v.x, v.y);
        fh[2 * k + 1] = cvt_pk(v.z, v.w);
    }

    const hv2 lk2 = hv2{ (_Float16)0.01f, (_Float16)0.01f };
    const hv2* Tt = reinterpret_cast<const hv2*>(s_c + WS_T);

    float acc = bo[0];
#pragma unroll
    for (int h = 0; h < HH; ++h) {               // h compile-time
        unsigned word = (h < 8) ? ew0 : ((h < 16) ? ew1 : ew2);
        int idx = (int)((word >> (4 * (h & 7))) & 0xfu);

        const hv2* Tr = Tt + (h * NEX + idx) * 6;
        hv2 tp[5] = { Tr[0], Tr[1], Tr[2], Tr[3], Tr[4] };

        // M[h]: 64B uniform row -> 4x ds_read_b128, pure SSA extract
        const float4* Mh4 = reinterpret_cast<const float4*>(s_c + WS_M + h * 16);
        float4 m0 = Mh4[0], m1 = Mh4[1], m2 = Mh4[2], m3 = Mh4[3];
        float mj[16] = { m0.x, m0.y, m0.z, m0.w,  m1.x, m1.y, m1.z, m1.w,
                         m2.x, m2.y, m2.z, m2.w,  m3.x, m3.y, m3.z, m3.w };

        // WB[h]: 32B uniform row -> 2x ds_read_b128, pure SSA extract
        const float4* wb4 = reinterpret_cast<const float4*>(s_c + WS_WB + h * 8);
        float4 w0 = wb4[0], w1 = wb4[1];
        float wj[5] = { w0.x, w0.y, w0.z, w0.w, w1.x };

        // f floats 3h..3h+2 out of fh[30] (pair index (3h)>>1, max 29)
        const int kb = (3 * h) >> 1;
        _Float16 x0, x1, x2;
        if ((h & 1) == 0) { x0 = fh[kb].x;  x1 = fh[kb].y;   x2 = fh[kb+1].x; }
        else              { x0 = fh[kb].y;  x1 = fh[kb+1].x; x2 = fh[kb+1].y; }
        hv2 g0 = hv2{ x0, x0 }, g1 = hv2{ x1, x1 }, g2 = hv2{ x2, x2 };

        float hacc = w1.y;                       // b2[h]
#pragma unroll
        for (int p = 0; p < 5; ++p) {
            hv2 v = g0 * __builtin_bit_cast(hv2, mj[p])      + tp[p];
            v = g1 * __builtin_bit_cast(hv2, mj[5 + p])  + v;
            v = g2 * __builtin_bit_cast(hv2, mj[10 + p]) + v;
            v = __builtin_elementwise_max(v, v * lk2);   // leaky
            hacc = fdot2f(v, __builtin_bit_cast(hv2, wj[p]), hacc);
        }
        acc = fmaf(softplus_fast(hacc), w1.z, acc);      // Wo[h]
    }

    out[item] = acc;                             // coalesced, no atomics
}

extern "C" void kernel_launch(void* const* d_in, const int* in_sizes, int n_in,
                              void* d_out, int out_size, void* d_ws, size_t ws_size,
                              hipStream_t stream) {
    const int*   e   = (const int*)  d_in[0];
    const float* f   = (const float*)d_in[1];
    const float* emb = (const float*)d_in[2];
    const float* Wf  = (const float*)d_in[3];
    const float* bf  = (const float*)d_in[4];
    const float* W1  = (const float*)d_in[5];
    const float* b1  = (const float*)d_in[6];
    const float* W2  = (const float*)d_in[7];
    const float* b2  = (const float*)d_in[8];
    const float* Wo  = (const float*)d_in[9];
    const float* bo  = (const float*)d_in[10];
    float* out = (float*)d_out;
    float* ws  = (float*)d_ws;

    int B = in_sizes[0] / HH;                    // e is (B, 20)

    int sblocks = (HH * NEX * 6 + 255) / 256;    // 7 blocks covers all tables
    airfit_setup<<<sblocks, 256, 0, stream>>>(emb, Wf, bf, W1, b1, W2, b2, Wo, ws);

    int blocks = (B + NT - 1) / NT;
    airfit_kernel<<<blocks, NT, 0, stream>>>(e, f, ws, bo, out, B);
}